// Round 9
// baseline (733.993 us; speedup 1.0000x reference)
//
#include <hip/hip_runtime.h>
#include <hip/hip_fp16.h>

// DeepNovo intensity-window gather, round 12: ABLATION / DECOMPOSITION.
// R11 dilation probe acquitted everything: WRITE_SIZE exact (no amp),
// FETCH 1.5MB (no RFO), occupancy 85% (2 blk/CU real), LDS conflicts 6.5%
// of wall. Four structural nulls (R7-R10) + no pipe >15% => stop guessing,
// ablate (skill: m177). Three kernels, one bench, Kernel_Name-split:
//   probe_store  x5  passes: R10 geometry+stores, gathers -> pp arithmetic.
//   probe_gather x16 passes: R10 staging+gathers, no stores (asm sink/pass).
//   intensity_kernel: byte-identical R10, runs last, owns correctness
//   (probes scribble on out; real kernel rewrites every element).
// Read: dur_per_pass(store) vs dur_per_pass(gather) names the wall;
// both-fast => interaction => next round software-pipelines gathers/stores.

#define MASS_H2O 18.01056f
#define MASS_NH3 17.02655f

typedef float floatx4 __attribute__((ext_vector_type(4)));

constexpr int MAX_MZ = 30000;
constexpr int WIN = 10;
constexpr int CPR = 520;
constexpr int BLOCK = 960;               // 15 waves
constexpr int GRID  = 494;               // 960*494 = 474240 = 520*912
constexpr int THREADS = GRID * BLOCK;
constexpr int ROW_STEP = THREADS / CPR;  // 912
constexpr int KMAX = 37;
constexpr int DROWS = 3;
constexpr int SPAD = 30004;
constexpr int PASS_S = 5;                // store-probe repetitions
constexpr int PASS_G = 16;               // gather-probe repetitions

// ---------- shared helpers (macro-free duplication kept minimal) ----------

__device__ __forceinline__ void stage_all(
    const float* __restrict__ spectrum, const float* __restrict__ pepmass,
    const float* __restrict__ prefix_mass, __half* sspec, float2* spmf,
    int blkR, int batch)
{
    const float2* sp2 = reinterpret_cast<const float2*>(spectrum);
    __half2* dst = reinterpret_cast<__half2*>(sspec);
#pragma unroll 4
    for (int i = threadIdx.x; i < MAX_MZ / 2; i += BLOCK) {
        float2 t = sp2[i];
        dst[i] = __floats2half2_rn(t.x, t.y);
    }
    if (threadIdx.x < (SPAD - MAX_MZ) / 2)
        dst[MAX_MZ / 2 + threadIdx.x] = __floats2half2_rn(0.f, 0.f);
    int i = threadIdx.x;
    if (i < DROWS * KMAX) {
        int d = i / KMAX;
        int k = i - d * KMAX;
        int r = blkR + d + k * ROW_STEP;
        float2 val = {0.0f, 0.0f};
        if (r < batch) { val.x = pepmass[r]; val.y = prefix_mass[r]; }
        spmf[i] = val;
    }
}

// ---------------- probe 1: store path only ----------------
__global__ __launch_bounds__(BLOCK, 8) void probe_store(
    const float* __restrict__ spectrum, const float* __restrict__ pepmass,
    const float* __restrict__ prefix_mass, const float* __restrict__ masses,
    const int* __restrict__ dir_p, float* __restrict__ out, int batch)
{
    __shared__ __half  sspec[SPAD];
    __shared__ float2  spmf[DROWS * KMAX];
    const int tid  = (int)blockIdx.x * BLOCK + (int)threadIdx.x;
    const int blkR = ((int)blockIdx.x * BLOCK) / CPR;
    stage_all(spectrum, pepmass, prefix_mass, sspec, spmf, blkR, batch);

    const int col  = tid % CPR;
    const int row0 = tid / CPR;
    const int doff = (row0 - blkR) * KMAX;
    const float ms = masses[col / 20];
    __syncthreads();
    // keep sspec allocation live (geometry parity with real kernel)
    float dsink = __half2float(sspec[threadIdx.x & 1023]);
    asm volatile("" :: "v"(dsink));

    const int n = (batch - row0 + ROW_STEP - 1) / ROW_STEP;
    floatx4* op = reinterpret_cast<floatx4*>(out) + tid;
    for (int p = 0; p < PASS_S; ++p) {
#pragma unroll 2
        for (int k = 0; k < n; ++k) {
            float2 pp = spmf[doff + k];
            float t = pp.y + ms;
            float u = pp.x - t;
            floatx4 r;
            r.x = t; r.y = u; r.z = t + u; r.w = t - u;
            op[(size_t)k * (size_t)THREADS] = r;        // same store pattern
        }
    }
}

// ---------------- probe 2: gather path only ----------------
__global__ __launch_bounds__(BLOCK, 8) void probe_gather(
    const float* __restrict__ spectrum, const float* __restrict__ pepmass,
    const float* __restrict__ prefix_mass, const float* __restrict__ masses,
    const int* __restrict__ dir_p, float* __restrict__ out, int batch)
{
    __shared__ __half  sspec[SPAD];
    __shared__ float2  spmf[DROWS * KMAX];
    const int tid  = (int)blockIdx.x * BLOCK + (int)threadIdx.x;
    const int blkR = ((int)blockIdx.x * BLOCK) / CPR;
    stage_all(spectrum, pepmass, prefix_mass, sspec, spmf, blkR, batch);

    const int col  = tid % CPR;
    const int row0 = tid / CPR;
    const int doff = (row0 - blkR) * KMAX;
    const int v = col / 20;
    const int q = col - v * 20;
    const float ms = masses[v];
    const bool lmb = (v > 2);
    const int dir = dir_p[0];

    const int e0 = 4 * q;
    const int ionA = e0 / 10,      wp0 = e0 - ionA * 10;
    const int ionB = (e0 + 2) / 10, wp1 = (e0 + 2) - ionB * 10;
    const bool suA = ((ionA >= 4) ^ (dir != 0));
    const bool suB = ((ionB >= 4) ^ (dir != 0));
    const int  kA = ionA & 3, kB = ionB & 3;
    const float ajA = (kA == 1) ? -MASS_H2O : (kA == 2) ? -MASS_NH3 : 0.0f;
    const float ajB = (kB == 1) ? -MASS_H2O : (kB == 2) ? -MASS_NH3 : 0.0f;
    const float mjA = (kA == 3) ? 5.0f : 10.0f;
    const float mjB = (kB == 3) ? 5.0f : 10.0f;
    __syncthreads();

    const int n = (batch - row0 + ROW_STEP - 1) / ROW_STEP;
    const uint32_t* spec32 = reinterpret_cast<const uint32_t*>(sspec);
    float acc = 0.0f;
    for (int p = 0; p < PASS_G; ++p) {
#pragma unroll 2
        for (int k = 0; k < n; ++k) {
            float2 pp = spmf[doff + k];
            float t = pp.y + ms;
            float u = pp.x - t;
            float baseA = suA ? u : t;
            float fA = (baseA + ajA) * mjA;
            int idxA = (int)rintf(fA) - (WIN / 2);
            bool vA = (unsigned)idxA <= (unsigned)(MAX_MZ - WIN);
            int safeA = vA ? idxA : 0;
            float okA = (vA && lmb) ? 1.0f : 0.0f;
            float baseB = suB ? u : t;
            float fB = (baseB + ajB) * mjB;
            int idxB = (int)rintf(fB) - (WIN / 2);
            bool vB = (unsigned)idxB <= (unsigned)(MAX_MZ - WIN);
            int safeB = vB ? idxB : 0;
            float okB = (vB && lmb) ? 1.0f : 0.0f;
            int h0 = safeA + wp0, h1 = safeB + wp1;
            int dw0 = h0 >> 1,    dw1 = h1 >> 1;
            uint32_t a0 = spec32[dw0], a1 = spec32[dw0 + 1];
            uint32_t b0 = spec32[dw1], b1 = spec32[dw1 + 1];
            uint32_t r0 = (uint32_t)(((((uint64_t)a1) << 32) | a0) >> ((h0 & 1) << 4));
            uint32_t r1 = (uint32_t)(((((uint64_t)b1) << 32) | b0) >> ((h1 & 1) << 4));
            __half2 hv0 = *reinterpret_cast<__half2*>(&r0);
            __half2 hv1 = *reinterpret_cast<__half2*>(&r1);
            acc += __low2float(hv0) * okA + __high2float(hv0) * okA
                 + __low2float(hv1) * okB + __high2float(hv1) * okB;
        }
        asm volatile("" :: "v"(acc));   // per-pass sink: no cross-pass CSE
    }
}

// ---------------- real kernel: byte-identical R10 ----------------
__global__ __launch_bounds__(BLOCK, 8) void intensity_kernel(
    const float* __restrict__ spectrum,
    const float* __restrict__ pepmass,
    const float* __restrict__ prefix_mass,
    const float* __restrict__ masses,
    const int*   __restrict__ dir_p,
    float* __restrict__ out,
    int batch)
{
    __shared__ __half  sspec[SPAD];
    __shared__ float2  spmf[DROWS * KMAX];
    const int tid  = (int)blockIdx.x * BLOCK + (int)threadIdx.x;
    const int blkR = ((int)blockIdx.x * BLOCK) / CPR;
    stage_all(spectrum, pepmass, prefix_mass, sspec, spmf, blkR, batch);

    const int col  = tid % CPR;
    const int row0 = tid / CPR;
    const int doff = (row0 - blkR) * KMAX;
    const int v = col / 20;
    const int q = col - v * 20;
    const float ms = masses[v];
    const bool lmb = (v > 2);
    const int dir = dir_p[0];

    const int e0 = 4 * q;
    const int ionA = e0 / 10,      wp0 = e0 - ionA * 10;
    const int ionB = (e0 + 2) / 10, wp1 = (e0 + 2) - ionB * 10;
    const bool suA = ((ionA >= 4) ^ (dir != 0));
    const bool suB = ((ionB >= 4) ^ (dir != 0));
    const int  kA = ionA & 3, kB = ionB & 3;
    const float ajA = (kA == 1) ? -MASS_H2O : (kA == 2) ? -MASS_NH3 : 0.0f;
    const float ajB = (kB == 1) ? -MASS_H2O : (kB == 2) ? -MASS_NH3 : 0.0f;
    const float mjA = (kA == 3) ? 5.0f : 10.0f;
    const float mjB = (kB == 3) ? 5.0f : 10.0f;
    __syncthreads();

    const int n = (batch - row0 + ROW_STEP - 1) / ROW_STEP;
    floatx4* op = reinterpret_cast<floatx4*>(out) + tid;
    const uint32_t* spec32 = reinterpret_cast<const uint32_t*>(sspec);

#pragma unroll 2
    for (int k = 0; k < n; ++k) {
        float2 pp = spmf[doff + k];
        float t = pp.y + ms;
        float u = pp.x - t;
        float baseA = suA ? u : t;
        float fA = (baseA + ajA) * mjA;
        int idxA = (int)rintf(fA) - (WIN / 2);
        bool vA = (unsigned)idxA <= (unsigned)(MAX_MZ - WIN);
        int safeA = vA ? idxA : 0;
        float okA = (vA && lmb) ? 1.0f : 0.0f;
        float baseB = suB ? u : t;
        float fB = (baseB + ajB) * mjB;
        int idxB = (int)rintf(fB) - (WIN / 2);
        bool vB = (unsigned)idxB <= (unsigned)(MAX_MZ - WIN);
        int safeB = vB ? idxB : 0;
        float okB = (vB && lmb) ? 1.0f : 0.0f;
        int h0 = safeA + wp0, h1 = safeB + wp1;
        int dw0 = h0 >> 1,    dw1 = h1 >> 1;
        uint32_t a0 = spec32[dw0], a1 = spec32[dw0 + 1];
        uint32_t b0 = spec32[dw1], b1 = spec32[dw1 + 1];
        uint32_t r0 = (uint32_t)(((((uint64_t)a1) << 32) | a0) >> ((h0 & 1) << 4));
        uint32_t r1 = (uint32_t)(((((uint64_t)b1) << 32) | b0) >> ((h1 & 1) << 4));
        __half2 hv0 = *reinterpret_cast<__half2*>(&r0);
        __half2 hv1 = *reinterpret_cast<__half2*>(&r1);

        floatx4 r;
        r.x = __low2float(hv0)  * okA;
        r.y = __high2float(hv0) * okA;
        r.z = __low2float(hv1)  * okB;
        r.w = __high2float(hv1) * okB;
        op[(size_t)k * (size_t)THREADS] = r;
    }
}

extern "C" void kernel_launch(void* const* d_in, const int* in_sizes, int n_in,
                              void* d_out, int out_size, void* d_ws, size_t ws_size,
                              hipStream_t stream) {
    const float* spectrum    = (const float*)d_in[0];
    const float* pepmass     = (const float*)d_in[1];
    const float* prefix_mass = (const float*)d_in[2];
    const float* masses      = (const float*)d_in[3];
    const int*   direction   = (const int*)d_in[4];
    float* out = (float*)d_out;
    int batch = in_sizes[1];             // 32768

    // probes first (scribble on out), real kernel last (rewrites all of out)
    probe_store<<<GRID, BLOCK, 0, stream>>>(
        spectrum, pepmass, prefix_mass, masses, direction, out, batch);
    probe_gather<<<GRID, BLOCK, 0, stream>>>(
        spectrum, pepmass, prefix_mass, masses, direction, out, batch);
    intensity_kernel<<<GRID, BLOCK, 0, stream>>>(
        spectrum, pepmass, prefix_mass, masses, direction, out, batch);
}

// Round 10
// 273.490 us; speedup vs baseline: 2.6838x; 2.6838x over previous
//
#include <hip/hip_runtime.h>
#include <hip/hip_fp16.h>

// DeepNovo intensity-window gather, round 13: PHASE-SPLIT (from R12 ablation).
// R12 decomposition: probe_gather (no stores) = 19us/pass @ VALUBusy ~100%;
// probe_store (no gathers) < 61us/pass (not in top-5; drain >= 4.5 TB/s);
// full kernel = 107us >> 19 + 45 and VALUBusy collapses to ~18%.
// => the per-iter gather->compute->store ALTERNATION convoys: store-data
// VGPRs reused next iter at VGPR<=64 force a tiny counted vmcnt (<=2 stores
// in flight/wave), so every iter waits a store-ack under congestion, and
// the wave can't prefetch next gathers meanwhile.
// R13: split phases within the wave. CHUNK=18 iterations computed into 72
// registers (gather phase = pure probe_gather behavior), then 18 stores
// back-to-back with NO register reuse between them (vmcnt guard 17, 9x
// amortized); x2 phases, phase-2 compute overlaps phase-1 drain.
// LDS (60.9KB) still caps at 2 blocks/CU -> VGPRs free to ~270/wave:
// __launch_bounds__(960) without the ",8" (which forced <=64 VGPR).
// vbuf statically indexed (skill rule #20). KIT=36 fixed; only k=35 store
// needs a row<batch guard (dead-iter gathers read zero-padded spmf, safe).
// Predict: VALUBusy 18 -> >=60%, kernel 107 -> 45-65us, dur ~210-235.
// Null (~270) kills the convoy theory -> re-probe store phase visibility.

#define MASS_H2O 18.01056f
#define MASS_NH3 17.02655f

typedef float floatx4 __attribute__((ext_vector_type(4)));

constexpr int MAX_MZ = 30000;
constexpr int WIN = 10;
constexpr int CPR = 520;
constexpr int BLOCK = 960;               // 15 waves
constexpr int GRID  = 494;               // 960*494 = 474240 = 520*912
constexpr int THREADS = GRID * BLOCK;
constexpr int ROW_STEP = THREADS / CPR;  // 912
constexpr int KIT = 36;                  // fixed iteration count (guard k=35)
constexpr int CHUNK = 18;                // iterations per phase
constexpr int KMAX = 37;
constexpr int DROWS = 3;
constexpr int SPAD = 30004;

__global__ __launch_bounds__(BLOCK) void intensity_kernel(
    const float* __restrict__ spectrum,
    const float* __restrict__ pepmass,
    const float* __restrict__ prefix_mass,
    const float* __restrict__ masses,
    const int*   __restrict__ dir_p,
    float* __restrict__ out,
    int batch)
{
    __shared__ __half  sspec[SPAD];           // 60,008 B -> 2 blocks/CU
    __shared__ float2  spmf[DROWS * KMAX];    // 888 B

    const int tid  = (int)blockIdx.x * BLOCK + (int)threadIdx.x;
    const int blkR = ((int)blockIdx.x * BLOCK) / CPR;

    // ---- stage spectrum fp32 -> fp16 into LDS ----
    {
        const float2* sp2 = reinterpret_cast<const float2*>(spectrum);
        __half2* dst = reinterpret_cast<__half2*>(sspec);
#pragma unroll 4
        for (int i = threadIdx.x; i < MAX_MZ / 2; i += BLOCK) {
            float2 t = sp2[i];
            dst[i] = __floats2half2_rn(t.x, t.y);
        }
        if (threadIdx.x < (SPAD - MAX_MZ) / 2)
            dst[MAX_MZ / 2 + threadIdx.x] = __floats2half2_rn(0.f, 0.f);
    }
    // ---- stage pm/pf rows (zero-padded past batch) ----
    {
        int i = threadIdx.x;
        if (i < DROWS * KMAX) {
            int d = i / KMAX;
            int k = i - d * KMAX;
            int r = blkR + d + k * ROW_STEP;
            float2 val = {0.0f, 0.0f};
            if (r < batch) { val.x = pepmass[r]; val.y = prefix_mass[r]; }
            spmf[i] = val;
        }
    }

    // ---- loop-invariant decode ----
    const int col  = tid % CPR;
    const int row0 = tid / CPR;
    const int doff = (row0 - blkR) * KMAX;
    const int v = col / 20;
    const int q = col - v * 20;
    const float ms = masses[v];
    const bool lmb = (v > 2);
    const int dir = dir_p[0];

    const int e0 = 4 * q;
    const int ionA = e0 / 10,       wp0 = e0 - ionA * 10;
    const int ionB = (e0 + 2) / 10, wp1 = (e0 + 2) - ionB * 10;
    const bool suA = ((ionA >= 4) ^ (dir != 0));
    const bool suB = ((ionB >= 4) ^ (dir != 0));
    const int  kA = ionA & 3, kB = ionB & 3;
    const float ajA = (kA == 1) ? -MASS_H2O : (kA == 2) ? -MASS_NH3 : 0.0f;
    const float ajB = (kB == 1) ? -MASS_H2O : (kB == 2) ? -MASS_NH3 : 0.0f;
    const float mjA = (kA == 3) ? 5.0f : 10.0f;     // mul*10, bit-exact vs ref
    const float mjB = (kB == 3) ? 5.0f : 10.0f;

    __syncthreads();

    const bool lastOk = (row0 + (KIT - 1) * ROW_STEP) < batch;
    floatx4* op = reinterpret_cast<floatx4*>(out) + tid;
    const uint32_t* spec32 = reinterpret_cast<const uint32_t*>(sspec);

    floatx4 vbuf[CHUNK];                 // 72 VGPRs, statically indexed

    for (int ph = 0; ph < KIT / CHUNK; ++ph) {
        const int kbase = ph * CHUNK;

        // ---------- gather/compute phase: no stores ----------
#pragma unroll
        for (int kk = 0; kk < CHUNK; ++kk) {
            const int k = kbase + kk;
            float2 pp = spmf[doff + k];
            float t = pp.y + ms;         // exact reference arithmetic
            float u = pp.x - t;

            float baseA = suA ? u : t;
            float fA = (baseA + ajA) * mjA;
            int idxA = (int)rintf(fA) - (WIN / 2);
            bool vA = (unsigned)idxA <= (unsigned)(MAX_MZ - WIN);
            int safeA = vA ? idxA : 0;
            float okA = (vA && lmb) ? 1.0f : 0.0f;

            float baseB = suB ? u : t;
            float fB = (baseB + ajB) * mjB;
            int idxB = (int)rintf(fB) - (WIN / 2);
            bool vB = (unsigned)idxB <= (unsigned)(MAX_MZ - WIN);
            int safeB = vB ? idxB : 0;
            float okB = (vB && lmb) ? 1.0f : 0.0f;

            int h0 = safeA + wp0, h1 = safeB + wp1;
            int dw0 = h0 >> 1,    dw1 = h1 >> 1;
            uint32_t a0 = spec32[dw0], a1 = spec32[dw0 + 1];   // ds_read2_b32
            uint32_t b0 = spec32[dw1], b1 = spec32[dw1 + 1];
            uint32_t r0 = (uint32_t)(((((uint64_t)a1) << 32) | a0) >> ((h0 & 1) << 4));
            uint32_t r1 = (uint32_t)(((((uint64_t)b1) << 32) | b0) >> ((h1 & 1) << 4));
            __half2 hv0 = *reinterpret_cast<__half2*>(&r0);
            __half2 hv1 = *reinterpret_cast<__half2*>(&r1);

            floatx4 r;
            r.x = __low2float(hv0)  * okA;
            r.y = __high2float(hv0) * okA;
            r.z = __low2float(hv1)  * okB;
            r.w = __high2float(hv1) * okB;
            vbuf[kk] = r;
        }

        // ---------- store phase: 18 back-to-back, no reg reuse ----------
#pragma unroll
        for (int kk = 0; kk < CHUNK; ++kk) {
            const int k = kbase + kk;
            if (k != KIT - 1 || lastOk)
                op[(size_t)k * (size_t)THREADS] = vbuf[kk];
        }
    }
}

extern "C" void kernel_launch(void* const* d_in, const int* in_sizes, int n_in,
                              void* d_out, int out_size, void* d_ws, size_t ws_size,
                              hipStream_t stream) {
    const float* spectrum    = (const float*)d_in[0];
    const float* pepmass     = (const float*)d_in[1];
    const float* prefix_mass = (const float*)d_in[2];
    const float* masses      = (const float*)d_in[3];
    const int*   direction   = (const int*)d_in[4];
    float* out = (float*)d_out;

    int batch = in_sizes[1];             // 32768
    intensity_kernel<<<GRID, BLOCK, 0, stream>>>(
        spectrum, pepmass, prefix_mass, masses, direction, out, batch);
}